// Round 6
// baseline (358.635 us; speedup 1.0000x reference)
//
#include <hip/hip_runtime.h>
#include <math.h>

#define EPA 2048      // edges per block in scatter pass
#define MAXB 16384    // LDS csr staging capacity (bucket avg ~8192, sd ~90)

typedef __attribute__((ext_vector_type(8))) short bf16x8;
typedef __attribute__((ext_vector_type(4))) float f32x4;

// ---------------- bf16 helpers (RNE) ----------------

__device__ inline float b2f(unsigned short u) {
  union { unsigned u32; float f; } c; c.u32 = ((unsigned)u) << 16; return c.f;
}
__device__ inline unsigned short f2b(float f) {
  union { float f; unsigned u; } c; c.f = f;
  unsigned r = c.u + 0x7fff + ((c.u >> 16) & 1);
  return (unsigned short)(r >> 16);
}

// ---------------- pass A0: coarse bucket histogram (bucket = dst>>8) ----------------
// Grid-stride, int4 loads: latency-hidden single read of dst.

__global__ __launch_bounds__(256) void k_bhist(const int* __restrict__ dst, int* __restrict__ bhist,
                                               int E, int NBKT) {
  __shared__ int hist[512];
  int tid = threadIdx.x;
  for (int i = tid; i < NBKT; i += 256) hist[i] = 0;
  __syncthreads();
  const int4* d4 = (const int4*)dst;
  int n4 = E >> 2;
  for (int i = blockIdx.x * 256 + tid; i < n4; i += gridDim.x * 256) {
    int4 v = d4[i];
    atomicAdd(&hist[v.x >> 8], 1);
    atomicAdd(&hist[v.y >> 8], 1);
    atomicAdd(&hist[v.z >> 8], 1);
    atomicAdd(&hist[v.w >> 8], 1);
  }
  if (blockIdx.x == 0 && tid < (E & 3)) atomicAdd(&bhist[dst[(E & ~3) + tid] >> 8], 1);
  __syncthreads();
  for (int i = tid; i < NBKT; i += 256) {
    int c = hist[i];
    if (c) atomicAdd(&bhist[i], c);
  }
}

// ---------------- bucket scan (single block): bbase, gcur, rowptr[N] ----------------

__global__ __launch_bounds__(256) void k_bscan(const int* __restrict__ bhist, int* __restrict__ bbase,
                                               int* __restrict__ gcur, int* __restrict__ rowptr,
                                               int E, int N, int NBKT) {
  __shared__ int a[512], c[512];
  int tid = threadIdx.x;
  int v0 = (tid < NBKT) ? bhist[tid] : 0;
  int v1 = (tid + 256 < NBKT) ? bhist[tid + 256] : 0;
  a[tid] = v0; a[tid + 256] = v1;
  __syncthreads();
  int* pin = a; int* pout = c;
  for (int st = 1; st < 512; st <<= 1) {
    pout[tid]       = pin[tid]       + ((tid >= st)       ? pin[tid - st]       : 0);
    pout[tid + 256] = pin[tid + 256] + ((tid + 256 >= st) ? pin[tid + 256 - st] : 0);
    __syncthreads();
    int* t = pin; pin = pout; pout = t;
  }
  if (tid < NBKT)       { int ex = pin[tid] - v0;       bbase[tid] = ex;       gcur[tid] = ex; }
  if (tid + 256 < NBKT) { int ex = pin[tid + 256] - v1; bbase[tid + 256] = ex; gcur[tid + 256] = ex; }
  if (tid == 0) { bbase[NBKT] = E; rowptr[N] = E; }
}

// ---------------- pass A: scatter packed (src<<8 | dstlocal) grouped by coarse bucket ----
// 1563 blocks, 8 edges/thread via int4 pairs (kept in registers across phases):
// 8 independent LDS-atomic + store chains in flight per thread.

__global__ __launch_bounds__(256) void k_bucket_scatter(const int* __restrict__ src, const int* __restrict__ dst,
                                                        int* __restrict__ gcur, unsigned* __restrict__ tmp,
                                                        int E, int NBKT) {
  __shared__ int hist[512], base[512];
  int tid = threadIdx.x;
  int ebeg = blockIdx.x * EPA;
  int eend = min(E, ebeg + EPA);
  for (int i = tid; i < NBKT; i += 256) hist[i] = 0;
  __syncthreads();
  int e0 = ebeg + tid * 8;
  int d0, d1, d2, d3, d4, d5, d6, d7;
  bool full = (e0 + 8 <= eend);
  if (full) {
    int4 a = *(const int4*)(dst + e0);
    int4 b = *(const int4*)(dst + e0 + 4);
    d0 = a.x; d1 = a.y; d2 = a.z; d3 = a.w; d4 = b.x; d5 = b.y; d6 = b.z; d7 = b.w;
    atomicAdd(&hist[d0 >> 8], 1); atomicAdd(&hist[d1 >> 8], 1);
    atomicAdd(&hist[d2 >> 8], 1); atomicAdd(&hist[d3 >> 8], 1);
    atomicAdd(&hist[d4 >> 8], 1); atomicAdd(&hist[d5 >> 8], 1);
    atomicAdd(&hist[d6 >> 8], 1); atomicAdd(&hist[d7 >> 8], 1);
  } else {
    for (int e = e0; e < eend; ++e) atomicAdd(&hist[dst[e] >> 8], 1);
  }
  __syncthreads();
  for (int i = tid; i < NBKT; i += 256) {
    int c = hist[i];
    base[i] = c ? atomicAdd(&gcur[i], c) : 0;
    hist[i] = 0;
  }
  __syncthreads();
  if (full) {
    int4 sa = *(const int4*)(src + e0);
    int4 sb = *(const int4*)(src + e0 + 4);
    int s0 = sa.x, s1 = sa.y, s2 = sa.z, s3 = sa.w, s4 = sb.x, s5 = sb.y, s6 = sb.z, s7 = sb.w;
    { int bkt = d0 >> 8; int o = base[bkt] + atomicAdd(&hist[bkt], 1); tmp[o] = ((unsigned)s0 << 8) | (unsigned)(d0 & 255); }
    { int bkt = d1 >> 8; int o = base[bkt] + atomicAdd(&hist[bkt], 1); tmp[o] = ((unsigned)s1 << 8) | (unsigned)(d1 & 255); }
    { int bkt = d2 >> 8; int o = base[bkt] + atomicAdd(&hist[bkt], 1); tmp[o] = ((unsigned)s2 << 8) | (unsigned)(d2 & 255); }
    { int bkt = d3 >> 8; int o = base[bkt] + atomicAdd(&hist[bkt], 1); tmp[o] = ((unsigned)s3 << 8) | (unsigned)(d3 & 255); }
    { int bkt = d4 >> 8; int o = base[bkt] + atomicAdd(&hist[bkt], 1); tmp[o] = ((unsigned)s4 << 8) | (unsigned)(d4 & 255); }
    { int bkt = d5 >> 8; int o = base[bkt] + atomicAdd(&hist[bkt], 1); tmp[o] = ((unsigned)s5 << 8) | (unsigned)(d5 & 255); }
    { int bkt = d6 >> 8; int o = base[bkt] + atomicAdd(&hist[bkt], 1); tmp[o] = ((unsigned)s6 << 8) | (unsigned)(d6 & 255); }
    { int bkt = d7 >> 8; int o = base[bkt] + atomicAdd(&hist[bkt], 1); tmp[o] = ((unsigned)s7 << 8) | (unsigned)(d7 & 255); }
  } else {
    for (int e = e0; e < eend; ++e) {
      int dd = dst[e];
      int bkt = dd >> 8;
      int o = base[bkt] + atomicAdd(&hist[bkt], 1);
      tmp[o] = ((unsigned)src[e] << 8) | (unsigned)(dd & 255);
    }
  }
}

// ---------------- pass B: per-bucket build: rowptr, dinv, csr (all LDS-local) ------------
// 1024 threads/block: 16 waves per bucket-block hides tmp-read + LDS-atomic latency.

__global__ __launch_bounds__(1024) void k_bucket_build(const unsigned* __restrict__ tmp, const int* __restrict__ bbase,
                                                       int* __restrict__ csr, int* __restrict__ rowptr,
                                                       float* __restrict__ dinv, int N) {
  int b = blockIdx.x;
  int tid = threadIdx.x;
  int node0 = b << 8;
  int nn = min(256, N - node0);
  int beg = bbase[b], end = bbase[b + 1], cnt = end - beg;
  __shared__ int h[256], off[256], cur[256];
  __shared__ int stage[MAXB];
  if (tid < 256) h[tid] = 0;
  __syncthreads();
  for (int e = beg + tid; e < end; e += 1024) atomicAdd(&h[tmp[e] & 255], 1);
  __syncthreads();
  int deg = 0;
  if (tid < 256) { deg = h[tid]; off[tid] = deg; }
  __syncthreads();
  for (int st = 1; st < 256; st <<= 1) {
    int t = 0;
    if (tid < 256 && tid >= st) t = off[tid - st];
    __syncthreads();
    if (tid < 256) off[tid] += t;
    __syncthreads();
  }
  if (tid < 256) {
    int excl = off[tid] - deg;
    cur[tid] = excl;
    if (tid < nn) {
      rowptr[node0 + tid] = beg + excl;
      dinv[node0 + tid] = rsqrtf((float)(deg + 1));  // +1 = self loop
    }
  }
  __syncthreads();
  if (cnt <= MAXB) {
    for (int e = beg + tid; e < end; e += 1024) {
      unsigned p = tmp[e];
      int pos = atomicAdd(&cur[p & 255], 1);
      stage[pos] = (int)(p >> 8);
    }
    __syncthreads();
    for (int k = tid; k < cnt; k += 1024) csr[beg + k] = stage[k];
  } else {  // safety fallback (never taken for uniform-random dst)
    for (int e = beg + tid; e < end; e += 1024) {
      unsigned p = tmp[e];
      int pos = atomicAdd(&cur[p & 255], 1);
      csr[beg + pos] = (int)(p >> 8);
    }
  }
}

// ---------------- MFMA GEMM + dinv prescale, bf16 sliced output ------------------------

template <int F_IN, int F_OUT>
__global__ __launch_bounds__(256) void k_gemm_mfma(const float* __restrict__ x, const float* __restrict__ W,
                                                   const float* __restrict__ dinv, unsigned short* __restrict__ g,
                                                   int N, int NT) {
  constexpr int NKS = F_IN / 32;   // K-steps of 32
  constexpr int NCT = F_OUT / 16;  // 16-col tiles (= output slices)
  int tid = threadIdx.x;
  int w = tid >> 6, lane = tid & 63;
  int lo = lane & 15, hi = lane >> 4;

  union U8 { bf16x8 v; unsigned u[4]; };
  U8 bf[NCT][NKS];
#pragma unroll
  for (int ct = 0; ct < NCT; ++ct)
#pragma unroll
    for (int ks = 0; ks < NKS; ++ks) {
      const float* wp = W + (size_t)(ks * 32 + hi * 8) * F_OUT + ct * 16 + lo;
      float f[8];
#pragma unroll
      for (int j = 0; j < 8; ++j) f[j] = wp[(size_t)j * F_OUT];
#pragma unroll
      for (int j = 0; j < 4; ++j)
        asm("v_cvt_pk_bf16_f32 %0, %1, %2" : "=v"(bf[ct][ks].u[j]) : "v"(f[2 * j]), "v"(f[2 * j + 1]));
    }

  for (int t = blockIdx.x * 4 + w; t < NT; t += gridDim.x * 4) {
    int row0 = t << 4;
    f32x4 acc[NCT];
#pragma unroll
    for (int ct = 0; ct < NCT; ++ct) acc[ct] = (f32x4){0.f, 0.f, 0.f, 0.f};
    int rl = row0 + lo; if (rl >= N) rl = N - 1;
    const float* xrow = x + (size_t)rl * F_IN;
#pragma unroll
    for (int ks = 0; ks < NKS; ++ks) {
      const float* xp = xrow + ks * 32 + hi * 8;
      float4 a0 = *(const float4*)xp;
      float4 a1 = *(const float4*)(xp + 4);
      U8 af;
      asm("v_cvt_pk_bf16_f32 %0, %1, %2" : "=v"(af.u[0]) : "v"(a0.x), "v"(a0.y));
      asm("v_cvt_pk_bf16_f32 %0, %1, %2" : "=v"(af.u[1]) : "v"(a0.z), "v"(a0.w));
      asm("v_cvt_pk_bf16_f32 %0, %1, %2" : "=v"(af.u[2]) : "v"(a1.x), "v"(a1.y));
      asm("v_cvt_pk_bf16_f32 %0, %1, %2" : "=v"(af.u[3]) : "v"(a1.z), "v"(a1.w));
#pragma unroll
      for (int ct = 0; ct < NCT; ++ct)
        acc[ct] = __builtin_amdgcn_mfma_f32_16x16x32_bf16(af.v, bf[ct][ks].v, acc[ct], 0, 0, 0);
    }
    float dvv[4];
    if (row0 + 16 <= N) {
      float4 d4 = *(const float4*)(dinv + row0 + (hi << 2));
      dvv[0] = d4.x; dvv[1] = d4.y; dvv[2] = d4.z; dvv[3] = d4.w;
    } else {
#pragma unroll
      for (int j = 0; j < 4; ++j) { int r = row0 + (hi << 2) + j; dvv[j] = dinv[r < N ? r : N - 1]; }
    }
#pragma unroll
    for (int ct = 0; ct < NCT; ++ct) {
      size_t sb = (size_t)ct * ((size_t)N * 16);
#pragma unroll
      for (int j = 0; j < 4; ++j) {
        int row = row0 + (hi << 2) + j;
        if (row < N) g[sb + (size_t)row * 16 + lo] = f2b(dvv[j] * acc[ct][j]);
      }
    }
  }
}

// ---------------- vector GEMM (layer 3 only: 32 -> 2) ----------------------------------

template <int F_IN, int F_OUT, int TPN, int ROWS>
__global__ __launch_bounds__(256) void k_gemm(const float* __restrict__ x, const float* __restrict__ W,
                                              const float* __restrict__ dinv, unsigned short* __restrict__ g, int N) {
  constexpr int VPT = F_OUT / TPN;
  constexpr int GROUPS = 256 / TPN;
  constexpr int NB = GROUPS * ROWS;
  __shared__ float ws[F_IN * F_OUT];
  __shared__ float xs[NB][F_IN];
  int tid = threadIdx.x;
  int base = blockIdx.x * NB;
  for (int i = tid; i < F_IN * F_OUT; i += 256) ws[i] = W[i];
  for (int i = tid; i < NB * F_IN; i += 256) {
    int r = i / F_IN, c = i - r * F_IN;
    int node = base + r;
    xs[r][c ^ (r & 31)] = (node < N) ? x[(size_t)node * F_IN + c] : 0.f;
  }
  __syncthreads();
  int fg = tid % TPN, f0 = fg * VPT;
  int ng = tid / TPN;
  int r0 = ng * ROWS;
  float acc[ROWS][VPT];
#pragma unroll
  for (int r = 0; r < ROWS; ++r)
#pragma unroll
    for (int j = 0; j < VPT; ++j) acc[r][j] = 0.f;
  for (int k = 0; k < F_IN; ++k) {
    float wv[VPT];
#pragma unroll
    for (int j = 0; j < VPT; ++j) wv[j] = ws[k * F_OUT + f0 + j];
#pragma unroll
    for (int r = 0; r < ROWS; ++r) {
      float xv = xs[r0 + r][k ^ ((r0 + r) & 31)];
#pragma unroll
      for (int j = 0; j < VPT; ++j) acc[r][j] += xv * wv[j];
    }
  }
#pragma unroll
  for (int r = 0; r < ROWS; ++r) {
    int node = base + r0 + r;
    if (node < N) {
      float dv = dinv[node];
#pragma unroll
      for (int j = 0; j < VPT; ++j) g[(size_t)node * F_OUT + f0 + j] = f2b(dv * acc[r][j]);
    }
  }
}

// ---------------- sliced CSR aggregation ------------------------------------------------

template <int FOUT, bool RELU>
__global__ __launch_bounds__(256) void k_aggs(const unsigned short* __restrict__ gs,
                                              const int* __restrict__ rowptr, const int* __restrict__ csr,
                                              const float* __restrict__ dinv, const float* __restrict__ bias,
                                              float* __restrict__ out, int N, int f0) {
  int t = blockIdx.x * 256 + threadIdx.x;
  int grp = t >> 3;
  if (grp >= N) return;
  unsigned subB = ((unsigned)t & 7u) << 2;
  const char* gb = (const char*)gs;
  unsigned u = *(const unsigned*)(gb + ((((unsigned)grp) << 5) + subB));
  float acc0 = __uint_as_float(u << 16);
  float acc1 = __uint_as_float(u & 0xffff0000u);
  int beg = rowptr[grp], end = rowptr[grp + 1];
  int j = beg;
  for (; j < end && (j & 3); ++j) {
    unsigned v = *(const unsigned*)(gb + ((((unsigned)csr[j]) << 5) + subB));
    acc0 += __uint_as_float(v << 16);
    acc1 += __uint_as_float(v & 0xffff0000u);
  }
  for (; j + 4 <= end; j += 4) {
    int4 ss = *(const int4*)(csr + j);
    unsigned v0 = *(const unsigned*)(gb + ((((unsigned)ss.x) << 5) + subB));
    unsigned v1 = *(const unsigned*)(gb + ((((unsigned)ss.y) << 5) + subB));
    unsigned v2 = *(const unsigned*)(gb + ((((unsigned)ss.z) << 5) + subB));
    unsigned v3 = *(const unsigned*)(gb + ((((unsigned)ss.w) << 5) + subB));
    acc0 += __uint_as_float(v0 << 16); acc1 += __uint_as_float(v0 & 0xffff0000u);
    acc0 += __uint_as_float(v1 << 16); acc1 += __uint_as_float(v1 & 0xffff0000u);
    acc0 += __uint_as_float(v2 << 16); acc1 += __uint_as_float(v2 & 0xffff0000u);
    acc0 += __uint_as_float(v3 << 16); acc1 += __uint_as_float(v3 & 0xffff0000u);
  }
  for (; j < end; ++j) {
    unsigned v = *(const unsigned*)(gb + ((((unsigned)csr[j]) << 5) + subB));
    acc0 += __uint_as_float(v << 16);
    acc1 += __uint_as_float(v & 0xffff0000u);
  }
  float dv = dinv[grp];
  int fg = f0 + (int)(subB >> 1);
  float r0 = fmaf(dv, acc0, bias[fg]);
  float r1 = fmaf(dv, acc1, bias[fg + 1]);
  if (RELU) { r0 = fmaxf(r0, 0.f); r1 = fmaxf(r1, 0.f); }
  *(float2*)(out + (size_t)grp * FOUT + fg) = make_float2(r0, r1);
}

// ---------------- final layer aggregation (F=2, packed 4B rows) + log_softmax --------

__global__ __launch_bounds__(256) void k_final(const unsigned* __restrict__ g2, const int* __restrict__ rowptr,
                                               const int* __restrict__ csr, const float* __restrict__ dinv,
                                               const float* __restrict__ bias, float* __restrict__ out, int N) {
  int i = blockIdx.x * 256 + threadIdx.x;
  if (i >= N) return;
  const char* gb = (const char*)g2;
  unsigned s = *(const unsigned*)(gb + (((unsigned)i) << 2));
  float a0 = __uint_as_float(s << 16), a1 = __uint_as_float(s & 0xffff0000u);
  int beg = rowptr[i], end = rowptr[i + 1];
  for (int j = beg; j < end; ++j) {
    unsigned p = *(const unsigned*)(gb + (((unsigned)csr[j]) << 2));
    a0 += __uint_as_float(p << 16);
    a1 += __uint_as_float(p & 0xffff0000u);
  }
  float dv = dinv[i];
  float v0 = fmaf(dv, a0, bias[0]);
  float v1 = fmaf(dv, a1, bias[1]);
  float m = fmaxf(v0, v1);
  float lse = m + logf(expf(v0 - m) + expf(v1 - m));
  out[2 * (size_t)i] = v0 - lse;
  out[2 * (size_t)i + 1] = v1 - lse;
}

// ---------------- launch ----------------

extern "C" void kernel_launch(void* const* d_in, const int* in_sizes, int n_in,
                              void* d_out, int out_size, void* d_ws, size_t ws_size,
                              hipStream_t stream) {
  const float* x  = (const float*)d_in[0];
  const int*   ei = (const int*)d_in[1];
  const float* W1 = (const float*)d_in[2];
  const float* b1 = (const float*)d_in[3];
  const float* W2 = (const float*)d_in[4];
  const float* b2 = (const float*)d_in[5];
  const float* W3 = (const float*)d_in[6];
  const float* b3 = (const float*)d_in[7];
  float* out = (float*)d_out;

  int N = in_sizes[0] / 128;  // 100000
  int E = in_sizes[1] / 2;    // 3200000
  const int* src = ei;        // edge_index[0]
  const int* dst = ei + E;    // edge_index[1]
  int NBKT = (N + 255) >> 8;  // 391 coarse buckets of 256 nodes
  int NT = (N + 15) / 16;     // 6250 row-tiles

  char* w = (char*)d_ws;
  size_t off = 0;
  auto carve = [&](size_t bytes) -> char* {
    char* p = w + off;
    off = (off + bytes + 255) & ~(size_t)255;
    return p;
  };
  float* dinv   = (float*)carve((size_t)N * 4);
  int*   rowptr = (int*)carve((size_t)(N + 1) * 4);
  int*   bhist  = (int*)carve(2048);
  int*   bbase  = (int*)carve(2048 + 4);
  int*   gcur   = (int*)carve(2048);
  int*   csr    = (int*)carve((size_t)E * 4);
  size_t gsz = (size_t)N * 64 * 2;               // bf16 g buffer (sliced layout)
  if ((size_t)E * 4 > gsz) gsz = (size_t)E * 4;  // doubles as packed pair buffer
  unsigned short* gbuf = (unsigned short*)carve(gsz);
  float* hbuf   = (float*)carve((size_t)N * 64 * 4);
  unsigned* tmp = (unsigned*)gbuf;  // pair buffer dead once k_bucket_build finishes
  (void)ws_size; (void)n_in; (void)out_size;

  hipMemsetAsync(bhist, 0, (size_t)NBKT * 4, stream);
  k_bhist<<<782, 256, 0, stream>>>(dst, bhist, E, NBKT);
  k_bscan<<<1, 256, 0, stream>>>(bhist, bbase, gcur, rowptr, E, N, NBKT);
  k_bucket_scatter<<<(E + EPA - 1) / EPA, 256, 0, stream>>>(src, dst, gcur, tmp, E, NBKT);
  k_bucket_build<<<NBKT, 1024, 0, stream>>>(tmp, bbase, csr, rowptr, dinv, N);

  unsigned aggGrid = (unsigned)(((long long)N * 8 + 255) / 256);

  // layer 1: 128 -> 64 MFMA, relu (4 slice passes, gather set 3.2MB L2-resident)
  k_gemm_mfma<128, 64><<<782, 256, 0, stream>>>(x, W1, dinv, gbuf, N, NT);
  for (int s = 0; s < 4; ++s)
    k_aggs<64, true><<<aggGrid, 256, 0, stream>>>(gbuf + (size_t)s * N * 16, rowptr, csr, dinv, b1, hbuf, N, s * 16);
  // layer 2: 64 -> 32 MFMA, relu (2 slice passes)
  k_gemm_mfma<64, 32><<<782, 256, 0, stream>>>(hbuf, W2, dinv, gbuf, N, NT);
  for (int s = 0; s < 2; ++s)
    k_aggs<32, true><<<aggGrid, 256, 0, stream>>>(gbuf + (size_t)s * N * 16, rowptr, csr, dinv, b2, hbuf, N, s * 16);
  // layer 3: 32 -> 2 vector, log_softmax (g2 = 400KB, L2-resident as-is)
  k_gemm<32, 2, 1, 1><<<(N + 255) / 256, 256, 0, stream>>>(hbuf, W3, dinv, gbuf, N);
  k_final<<<(unsigned)((N + 255) / 256), 256, 0, stream>>>((const unsigned*)gbuf, rowptr, csr, dinv, b3, out, N);
}

// Round 7
// 322.588 us; speedup vs baseline: 1.1117x; 1.1117x over previous
//
#include <hip/hip_runtime.h>
#include <math.h>

#define EPB 8192      // edges per block in scatter pass
#define MAXB 16384    // LDS csr staging capacity (bucket avg ~8192, sd ~90)

typedef __attribute__((ext_vector_type(8))) short bf16x8;
typedef __attribute__((ext_vector_type(4))) float f32x4;

// ---------------- bf16 helpers (RNE) ----------------

__device__ inline float b2f(unsigned short u) {
  union { unsigned u32; float f; } c; c.u32 = ((unsigned)u) << 16; return c.f;
}
__device__ inline unsigned short f2b(float f) {
  union { float f; unsigned u; } c; c.f = f;
  unsigned r = c.u + 0x7fff + ((c.u >> 16) & 1);
  return (unsigned short)(r >> 16);
}

// ---------------- pass A0: coarse bucket histogram (bucket = dst>>8) ----------------

__global__ __launch_bounds__(256) void k_bhist(const int* __restrict__ dst, int* __restrict__ bhist,
                                               int E, int NBKT) {
  __shared__ int hist[512];
  int tid = threadIdx.x;
  for (int i = tid; i < NBKT; i += 256) hist[i] = 0;
  __syncthreads();
  const int4* d4 = (const int4*)dst;
  int n4 = E >> 2;
  for (int i = blockIdx.x * 256 + tid; i < n4; i += gridDim.x * 256) {
    int4 v = d4[i];
    atomicAdd(&hist[v.x >> 8], 1);
    atomicAdd(&hist[v.y >> 8], 1);
    atomicAdd(&hist[v.z >> 8], 1);
    atomicAdd(&hist[v.w >> 8], 1);
  }
  if (blockIdx.x == 0 && tid < (E & 3)) atomicAdd(&bhist[dst[(E & ~3) + tid] >> 8], 1);
  __syncthreads();
  for (int i = tid; i < NBKT; i += 256) {
    int c = hist[i];
    if (c) atomicAdd(&bhist[i], c);
  }
}

// ---------------- bucket scan (single block): bbase, gcur, rowptr[N] ----------------

__global__ __launch_bounds__(256) void k_bscan(const int* __restrict__ bhist, int* __restrict__ bbase,
                                               int* __restrict__ gcur, int* __restrict__ rowptr,
                                               int E, int N, int NBKT) {
  __shared__ int a[512], c[512];
  int tid = threadIdx.x;
  int v0 = (tid < NBKT) ? bhist[tid] : 0;
  int v1 = (tid + 256 < NBKT) ? bhist[tid + 256] : 0;
  a[tid] = v0; a[tid + 256] = v1;
  __syncthreads();
  int* pin = a; int* pout = c;
  for (int st = 1; st < 512; st <<= 1) {
    pout[tid]       = pin[tid]       + ((tid >= st)       ? pin[tid - st]       : 0);
    pout[tid + 256] = pin[tid + 256] + ((tid + 256 >= st) ? pin[tid + 256 - st] : 0);
    __syncthreads();
    int* t = pin; pin = pout; pout = t;
  }
  if (tid < NBKT)       { int ex = pin[tid] - v0;       bbase[tid] = ex;       gcur[tid] = ex; }
  if (tid + 256 < NBKT) { int ex = pin[tid + 256] - v1; bbase[tid + 256] = ex; gcur[tid + 256] = ex; }
  if (tid == 0) { bbase[NBKT] = E; rowptr[N] = E; }
}

// ---------------- pass A: LDS counting-sort by coarse bucket, run-coalesced writeback ----
// 512 threads x 16 edges (registers, full unroll). Block-local sort into stage[] via
// hist-scan + LDS atomics; writeback streams each bucket's run contiguously (no
// atomic->store dependence, dense coalesced writes).

__global__ __launch_bounds__(512) void k_bucket_scatter(const int* __restrict__ src, const int* __restrict__ dst,
                                                        int* __restrict__ gcur, unsigned* __restrict__ tmp,
                                                        int E, int NBKT) {
  __shared__ int hist[512], base[512], loff[512], cur[512];
  __shared__ int sa[512], sc[512];
  __shared__ unsigned stage[EPB];
  int tid = threadIdx.x;
  int ebeg = blockIdx.x * EPB;
  int eend = min(E, ebeg + EPB);
  hist[tid] = 0;
  __syncthreads();
  int e0 = ebeg + tid * 16;
  int nE = eend - e0; if (nE < 0) nE = 0; if (nE > 16) nE = 16;
  int d[16], s[16];
  if (nE == 16) {
#pragma unroll
    for (int q = 0; q < 4; ++q) {
      int4 dv = *(const int4*)(dst + e0 + q * 4);
      int4 sv = *(const int4*)(src + e0 + q * 4);
      d[q * 4 + 0] = dv.x; d[q * 4 + 1] = dv.y; d[q * 4 + 2] = dv.z; d[q * 4 + 3] = dv.w;
      s[q * 4 + 0] = sv.x; s[q * 4 + 1] = sv.y; s[q * 4 + 2] = sv.z; s[q * 4 + 3] = sv.w;
    }
  } else {
#pragma unroll
    for (int k = 0; k < 16; ++k) {
      if (k < nE) { d[k] = dst[e0 + k]; s[k] = src[e0 + k]; } else { d[k] = 0; s[k] = 0; }
    }
  }
#pragma unroll
  for (int k = 0; k < 16; ++k) if (k < nE) atomicAdd(&hist[d[k] >> 8], 1);
  __syncthreads();
  int hc = hist[tid];
  sa[tid] = hc;
  base[tid] = (tid < NBKT && hc) ? atomicAdd(&gcur[tid], hc) : 0;
  __syncthreads();
  int* pin = sa; int* pout = sc;
  for (int st = 1; st < 512; st <<= 1) {
    pout[tid] = pin[tid] + ((tid >= st) ? pin[tid - st] : 0);
    __syncthreads();
    int* t = pin; pin = pout; pout = t;
  }
  int excl = pin[tid] - hc;
  loff[tid] = excl; cur[tid] = excl;
  __syncthreads();
#pragma unroll
  for (int k = 0; k < 16; ++k) if (k < nE) {
    int bkt = d[k] >> 8;
    int pos = atomicAdd(&cur[bkt], 1);
    stage[pos] = ((unsigned)s[k] << 8) | (unsigned)(d[k] & 255);
  }
  __syncthreads();
  int wv = tid >> 6, ln = tid & 63;
  for (int i = wv; i < NBKT; i += 8) {
    int c = hist[i], lo = loff[i], gb = base[i];
    for (int k = ln; k < c; k += 64) tmp[gb + k] = stage[lo + k];
  }
}

// ---------------- pass B: per-bucket build: rowptr, dinv, csr (all LDS-local) ------------

__global__ __launch_bounds__(512) void k_bucket_build(const unsigned* __restrict__ tmp, const int* __restrict__ bbase,
                                                      int* __restrict__ csr, int* __restrict__ rowptr,
                                                      float* __restrict__ dinv, int N) {
  int b = blockIdx.x;
  int tid = threadIdx.x;
  int node0 = b << 8;
  int nn = min(256, N - node0);
  int beg = bbase[b], end = bbase[b + 1], cnt = end - beg;
  __shared__ int h[256], off[256], cur[256];
  __shared__ int stage[MAXB];
  if (tid < 256) h[tid] = 0;
  __syncthreads();
  for (int e = beg + tid; e < end; e += 512) atomicAdd(&h[tmp[e] & 255], 1);
  __syncthreads();
  int deg = 0;
  if (tid < 256) { deg = h[tid]; off[tid] = deg; }
  __syncthreads();
  for (int st = 1; st < 256; st <<= 1) {
    int t = 0;
    if (tid < 256 && tid >= st) t = off[tid - st];
    __syncthreads();
    if (tid < 256) off[tid] += t;
    __syncthreads();
  }
  if (tid < 256) {
    int excl = off[tid] - deg;
    cur[tid] = excl;
    if (tid < nn) {
      rowptr[node0 + tid] = beg + excl;
      dinv[node0 + tid] = rsqrtf((float)(deg + 1));  // +1 = self loop
    }
  }
  __syncthreads();
  if (cnt <= MAXB) {
    for (int e = beg + tid; e < end; e += 512) {
      unsigned p = tmp[e];
      int pos = atomicAdd(&cur[p & 255], 1);
      stage[pos] = (int)(p >> 8);
    }
    __syncthreads();
    for (int k = tid; k < cnt; k += 512) csr[beg + k] = stage[k];
  } else {  // safety fallback (never taken for uniform-random dst)
    for (int e = beg + tid; e < end; e += 512) {
      unsigned p = tmp[e];
      int pos = atomicAdd(&cur[p & 255], 1);
      csr[beg + pos] = (int)(p >> 8);
    }
  }
}

// ---------------- MFMA GEMM + dinv prescale, bf16 sliced output ------------------------

template <int F_IN, int F_OUT>
__global__ __launch_bounds__(256) void k_gemm_mfma(const float* __restrict__ x, const float* __restrict__ W,
                                                   const float* __restrict__ dinv, unsigned short* __restrict__ g,
                                                   int N, int NT) {
  constexpr int NKS = F_IN / 32;   // K-steps of 32
  constexpr int NCT = F_OUT / 16;  // 16-col tiles (= output slices)
  int tid = threadIdx.x;
  int w = tid >> 6, lane = tid & 63;
  int lo = lane & 15, hi = lane >> 4;

  union U8 { bf16x8 v; unsigned u[4]; };
  U8 bf[NCT][NKS];
#pragma unroll
  for (int ct = 0; ct < NCT; ++ct)
#pragma unroll
    for (int ks = 0; ks < NKS; ++ks) {
      const float* wp = W + (size_t)(ks * 32 + hi * 8) * F_OUT + ct * 16 + lo;
      float f[8];
#pragma unroll
      for (int j = 0; j < 8; ++j) f[j] = wp[(size_t)j * F_OUT];
#pragma unroll
      for (int j = 0; j < 4; ++j)
        asm("v_cvt_pk_bf16_f32 %0, %1, %2" : "=v"(bf[ct][ks].u[j]) : "v"(f[2 * j]), "v"(f[2 * j + 1]));
    }

  for (int t = blockIdx.x * 4 + w; t < NT; t += gridDim.x * 4) {
    int row0 = t << 4;
    f32x4 acc[NCT];
#pragma unroll
    for (int ct = 0; ct < NCT; ++ct) acc[ct] = (f32x4){0.f, 0.f, 0.f, 0.f};
    int rl = row0 + lo; if (rl >= N) rl = N - 1;
    const float* xrow = x + (size_t)rl * F_IN;
#pragma unroll
    for (int ks = 0; ks < NKS; ++ks) {
      const float* xp = xrow + ks * 32 + hi * 8;
      float4 a0 = *(const float4*)xp;
      float4 a1 = *(const float4*)(xp + 4);
      U8 af;
      asm("v_cvt_pk_bf16_f32 %0, %1, %2" : "=v"(af.u[0]) : "v"(a0.x), "v"(a0.y));
      asm("v_cvt_pk_bf16_f32 %0, %1, %2" : "=v"(af.u[1]) : "v"(a0.z), "v"(a0.w));
      asm("v_cvt_pk_bf16_f32 %0, %1, %2" : "=v"(af.u[2]) : "v"(a1.x), "v"(a1.y));
      asm("v_cvt_pk_bf16_f32 %0, %1, %2" : "=v"(af.u[3]) : "v"(a1.z), "v"(a1.w));
#pragma unroll
      for (int ct = 0; ct < NCT; ++ct)
        acc[ct] = __builtin_amdgcn_mfma_f32_16x16x32_bf16(af.v, bf[ct][ks].v, acc[ct], 0, 0, 0);
    }
    float dvv[4];
    if (row0 + 16 <= N) {
      float4 d4 = *(const float4*)(dinv + row0 + (hi << 2));
      dvv[0] = d4.x; dvv[1] = d4.y; dvv[2] = d4.z; dvv[3] = d4.w;
    } else {
#pragma unroll
      for (int j = 0; j < 4; ++j) { int r = row0 + (hi << 2) + j; dvv[j] = dinv[r < N ? r : N - 1]; }
    }
#pragma unroll
    for (int ct = 0; ct < NCT; ++ct) {
      size_t sb = (size_t)ct * ((size_t)N * 16);
#pragma unroll
      for (int j = 0; j < 4; ++j) {
        int row = row0 + (hi << 2) + j;
        if (row < N) g[sb + (size_t)row * 16 + lo] = f2b(dvv[j] * acc[ct][j]);
      }
    }
  }
}

// ---------------- vector GEMM (layer 3 only: 32 -> 2) ----------------------------------

template <int F_IN, int F_OUT, int TPN, int ROWS>
__global__ __launch_bounds__(256) void k_gemm(const float* __restrict__ x, const float* __restrict__ W,
                                              const float* __restrict__ dinv, unsigned short* __restrict__ g, int N) {
  constexpr int VPT = F_OUT / TPN;
  constexpr int GROUPS = 256 / TPN;
  constexpr int NB = GROUPS * ROWS;
  __shared__ float ws[F_IN * F_OUT];
  __shared__ float xs[NB][F_IN];
  int tid = threadIdx.x;
  int base = blockIdx.x * NB;
  for (int i = tid; i < F_IN * F_OUT; i += 256) ws[i] = W[i];
  for (int i = tid; i < NB * F_IN; i += 256) {
    int r = i / F_IN, c = i - r * F_IN;
    int node = base + r;
    xs[r][c ^ (r & 31)] = (node < N) ? x[(size_t)node * F_IN + c] : 0.f;
  }
  __syncthreads();
  int fg = tid % TPN, f0 = fg * VPT;
  int ng = tid / TPN;
  int r0 = ng * ROWS;
  float acc[ROWS][VPT];
#pragma unroll
  for (int r = 0; r < ROWS; ++r)
#pragma unroll
    for (int j = 0; j < VPT; ++j) acc[r][j] = 0.f;
  for (int k = 0; k < F_IN; ++k) {
    float wv[VPT];
#pragma unroll
    for (int j = 0; j < VPT; ++j) wv[j] = ws[k * F_OUT + f0 + j];
#pragma unroll
    for (int r = 0; r < ROWS; ++r) {
      float xv = xs[r0 + r][k ^ ((r0 + r) & 31)];
#pragma unroll
      for (int j = 0; j < VPT; ++j) acc[r][j] += xv * wv[j];
    }
  }
#pragma unroll
  for (int r = 0; r < ROWS; ++r) {
    int node = base + r0 + r;
    if (node < N) {
      float dv = dinv[node];
#pragma unroll
      for (int j = 0; j < VPT; ++j) g[(size_t)node * F_OUT + f0 + j] = f2b(dv * acc[r][j]);
    }
  }
}

// ---------------- sliced CSR aggregation ------------------------------------------------

template <int FOUT, bool RELU>
__global__ __launch_bounds__(256) void k_aggs(const unsigned short* __restrict__ gs,
                                              const int* __restrict__ rowptr, const int* __restrict__ csr,
                                              const float* __restrict__ dinv, const float* __restrict__ bias,
                                              float* __restrict__ out, int N, int f0) {
  int t = blockIdx.x * 256 + threadIdx.x;
  int grp = t >> 3;
  if (grp >= N) return;
  unsigned subB = ((unsigned)t & 7u) << 2;
  const char* gb = (const char*)gs;
  unsigned u = *(const unsigned*)(gb + ((((unsigned)grp) << 5) + subB));
  float acc0 = __uint_as_float(u << 16);
  float acc1 = __uint_as_float(u & 0xffff0000u);
  int beg = rowptr[grp], end = rowptr[grp + 1];
  int j = beg;
  for (; j < end && (j & 3); ++j) {
    unsigned v = *(const unsigned*)(gb + ((((unsigned)csr[j]) << 5) + subB));
    acc0 += __uint_as_float(v << 16);
    acc1 += __uint_as_float(v & 0xffff0000u);
  }
  for (; j + 4 <= end; j += 4) {
    int4 ss = *(const int4*)(csr + j);
    unsigned v0 = *(const unsigned*)(gb + ((((unsigned)ss.x) << 5) + subB));
    unsigned v1 = *(const unsigned*)(gb + ((((unsigned)ss.y) << 5) + subB));
    unsigned v2 = *(const unsigned*)(gb + ((((unsigned)ss.z) << 5) + subB));
    unsigned v3 = *(const unsigned*)(gb + ((((unsigned)ss.w) << 5) + subB));
    acc0 += __uint_as_float(v0 << 16); acc1 += __uint_as_float(v0 & 0xffff0000u);
    acc0 += __uint_as_float(v1 << 16); acc1 += __uint_as_float(v1 & 0xffff0000u);
    acc0 += __uint_as_float(v2 << 16); acc1 += __uint_as_float(v2 & 0xffff0000u);
    acc0 += __uint_as_float(v3 << 16); acc1 += __uint_as_float(v3 & 0xffff0000u);
  }
  for (; j < end; ++j) {
    unsigned v = *(const unsigned*)(gb + ((((unsigned)csr[j]) << 5) + subB));
    acc0 += __uint_as_float(v << 16);
    acc1 += __uint_as_float(v & 0xffff0000u);
  }
  float dv = dinv[grp];
  int fg = f0 + (int)(subB >> 1);
  float r0 = fmaf(dv, acc0, bias[fg]);
  float r1 = fmaf(dv, acc1, bias[fg + 1]);
  if (RELU) { r0 = fmaxf(r0, 0.f); r1 = fmaxf(r1, 0.f); }
  *(float2*)(out + (size_t)grp * FOUT + fg) = make_float2(r0, r1);
}

// ---------------- final layer aggregation (F=2, packed 4B rows) + log_softmax --------

__global__ __launch_bounds__(256) void k_final(const unsigned* __restrict__ g2, const int* __restrict__ rowptr,
                                               const int* __restrict__ csr, const float* __restrict__ dinv,
                                               const float* __restrict__ bias, float* __restrict__ out, int N) {
  int i = blockIdx.x * 256 + threadIdx.x;
  if (i >= N) return;
  const char* gb = (const char*)g2;
  unsigned s = *(const unsigned*)(gb + (((unsigned)i) << 2));
  float a0 = __uint_as_float(s << 16), a1 = __uint_as_float(s & 0xffff0000u);
  int beg = rowptr[i], end = rowptr[i + 1];
  for (int j = beg; j < end; ++j) {
    unsigned p = *(const unsigned*)(gb + (((unsigned)csr[j]) << 2));
    a0 += __uint_as_float(p << 16);
    a1 += __uint_as_float(p & 0xffff0000u);
  }
  float dv = dinv[i];
  float v0 = fmaf(dv, a0, bias[0]);
  float v1 = fmaf(dv, a1, bias[1]);
  float m = fmaxf(v0, v1);
  float lse = m + logf(expf(v0 - m) + expf(v1 - m));
  out[2 * (size_t)i] = v0 - lse;
  out[2 * (size_t)i + 1] = v1 - lse;
}

// ---------------- launch ----------------

extern "C" void kernel_launch(void* const* d_in, const int* in_sizes, int n_in,
                              void* d_out, int out_size, void* d_ws, size_t ws_size,
                              hipStream_t stream) {
  const float* x  = (const float*)d_in[0];
  const int*   ei = (const int*)d_in[1];
  const float* W1 = (const float*)d_in[2];
  const float* b1 = (const float*)d_in[3];
  const float* W2 = (const float*)d_in[4];
  const float* b2 = (const float*)d_in[5];
  const float* W3 = (const float*)d_in[6];
  const float* b3 = (const float*)d_in[7];
  float* out = (float*)d_out;

  int N = in_sizes[0] / 128;  // 100000
  int E = in_sizes[1] / 2;    // 3200000
  const int* src = ei;        // edge_index[0]
  const int* dst = ei + E;    // edge_index[1]
  int NBKT = (N + 255) >> 8;  // 391 coarse buckets of 256 nodes
  int NT = (N + 15) / 16;     // 6250 row-tiles

  char* w = (char*)d_ws;
  size_t off = 0;
  auto carve = [&](size_t bytes) -> char* {
    char* p = w + off;
    off = (off + bytes + 255) & ~(size_t)255;
    return p;
  };
  float* dinv   = (float*)carve((size_t)N * 4);
  int*   rowptr = (int*)carve((size_t)(N + 1) * 4);
  int*   bhist  = (int*)carve(2048);
  int*   bbase  = (int*)carve(2048 + 4);
  int*   gcur   = (int*)carve(2048);
  int*   csr    = (int*)carve((size_t)E * 4);
  size_t gsz = (size_t)N * 64 * 2;               // bf16 g buffer (sliced layout)
  if ((size_t)E * 4 > gsz) gsz = (size_t)E * 4;  // doubles as packed pair buffer
  unsigned short* gbuf = (unsigned short*)carve(gsz);
  float* hbuf   = (float*)carve((size_t)N * 64 * 4);
  unsigned* tmp = (unsigned*)gbuf;  // pair buffer dead once k_bucket_build finishes
  (void)ws_size; (void)n_in; (void)out_size;

  hipMemsetAsync(bhist, 0, (size_t)NBKT * 4, stream);
  k_bhist<<<782, 256, 0, stream>>>(dst, bhist, E, NBKT);
  k_bscan<<<1, 256, 0, stream>>>(bhist, bbase, gcur, rowptr, E, N, NBKT);
  k_bucket_scatter<<<(E + EPB - 1) / EPB, 512, 0, stream>>>(src, dst, gcur, tmp, E, NBKT);
  k_bucket_build<<<NBKT, 512, 0, stream>>>(tmp, bbase, csr, rowptr, dinv, N);

  unsigned aggGrid = (unsigned)(((long long)N * 8 + 255) / 256);

  // layer 1: 128 -> 64 MFMA, relu (4 slice passes, gather set 3.2MB L2-resident)
  k_gemm_mfma<128, 64><<<782, 256, 0, stream>>>(x, W1, dinv, gbuf, N, NT);
  for (int s = 0; s < 4; ++s)
    k_aggs<64, true><<<aggGrid, 256, 0, stream>>>(gbuf + (size_t)s * N * 16, rowptr, csr, dinv, b1, hbuf, N, s * 16);
  // layer 2: 64 -> 32 MFMA, relu (2 slice passes)
  k_gemm_mfma<64, 32><<<782, 256, 0, stream>>>(hbuf, W2, dinv, gbuf, N, NT);
  for (int s = 0; s < 2; ++s)
    k_aggs<32, true><<<aggGrid, 256, 0, stream>>>(gbuf + (size_t)s * N * 16, rowptr, csr, dinv, b2, hbuf, N, s * 16);
  // layer 3: 32 -> 2 vector, log_softmax (g2 = 400KB, L2-resident as-is)
  k_gemm<32, 2, 1, 1><<<(N + 255) / 256, 256, 0, stream>>>(hbuf, W3, dinv, gbuf, N);
  k_final<<<(unsigned)((N + 255) / 256), 256, 0, stream>>>((const unsigned*)gbuf, rowptr, csr, dinv, b3, out, N);
}

// Round 8
// 300.917 us; speedup vs baseline: 1.1918x; 1.0720x over previous
//
#include <hip/hip_runtime.h>
#include <math.h>

#define EPB 8192      // edges per block in scatter pass
#define MAXB 16384    // LDS csr staging capacity (bucket avg ~8192, sd ~90)

typedef __attribute__((ext_vector_type(8))) short bf16x8;
typedef __attribute__((ext_vector_type(4))) float f32x4;

// ---------------- bf16 helpers (RNE) ----------------

__device__ inline float b2f(unsigned short u) {
  union { unsigned u32; float f; } c; c.u32 = ((unsigned)u) << 16; return c.f;
}
__device__ inline unsigned short f2b(float f) {
  union { float f; unsigned u; } c; c.f = f;
  unsigned r = c.u + 0x7fff + ((c.u >> 16) & 1);
  return (unsigned short)(r >> 16);
}

// ---------------- pass A0: coarse bucket histogram (bucket = dst>>8) ----------------

__global__ __launch_bounds__(256) void k_bhist(const int* __restrict__ dst, int* __restrict__ bhist,
                                               int E, int NBKT) {
  __shared__ int hist[512];
  int tid = threadIdx.x;
  for (int i = tid; i < NBKT; i += 256) hist[i] = 0;
  __syncthreads();
  const int4* d4 = (const int4*)dst;
  int n4 = E >> 2;
  for (int i = blockIdx.x * 256 + tid; i < n4; i += gridDim.x * 256) {
    int4 v = d4[i];
    atomicAdd(&hist[v.x >> 8], 1);
    atomicAdd(&hist[v.y >> 8], 1);
    atomicAdd(&hist[v.z >> 8], 1);
    atomicAdd(&hist[v.w >> 8], 1);
  }
  if (blockIdx.x == 0 && tid < (E & 3)) atomicAdd(&bhist[dst[(E & ~3) + tid] >> 8], 1);
  __syncthreads();
  for (int i = tid; i < NBKT; i += 256) {
    int c = hist[i];
    if (c) atomicAdd(&bhist[i], c);
  }
}

// ---------------- bucket scan (single block): bbase, gcur, rowptr[N] ----------------

__global__ __launch_bounds__(256) void k_bscan(const int* __restrict__ bhist, int* __restrict__ bbase,
                                               int* __restrict__ gcur, int* __restrict__ rowptr,
                                               int E, int N, int NBKT) {
  __shared__ int a[512], c[512];
  int tid = threadIdx.x;
  int v0 = (tid < NBKT) ? bhist[tid] : 0;
  int v1 = (tid + 256 < NBKT) ? bhist[tid + 256] : 0;
  a[tid] = v0; a[tid + 256] = v1;
  __syncthreads();
  int* pin = a; int* pout = c;
  for (int st = 1; st < 512; st <<= 1) {
    pout[tid]       = pin[tid]       + ((tid >= st)       ? pin[tid - st]       : 0);
    pout[tid + 256] = pin[tid + 256] + ((tid + 256 >= st) ? pin[tid + 256 - st] : 0);
    __syncthreads();
    int* t = pin; pin = pout; pout = t;
  }
  if (tid < NBKT)       { int ex = pin[tid] - v0;       bbase[tid] = ex;       gcur[tid] = ex; }
  if (tid + 256 < NBKT) { int ex = pin[tid + 256] - v1; bbase[tid + 256] = ex; gcur[tid + 256] = ex; }
  if (tid == 0) { bbase[NBKT] = E; rowptr[N] = E; }
}

// ---------------- pass A: LDS counting-sort by coarse bucket, run-coalesced writeback ----
// Rank-capture: the histogram atomicAdd's return value IS the within-block rank, so the
// placement round is pure LDS stores (no second atomic round).

__global__ __launch_bounds__(512) void k_bucket_scatter(const int* __restrict__ src, const int* __restrict__ dst,
                                                        int* __restrict__ gcur, unsigned* __restrict__ tmp,
                                                        int E, int NBKT) {
  __shared__ int hist[512], base[512], loff[512];
  __shared__ int sa[512], sc[512];
  __shared__ unsigned stage[EPB];
  int tid = threadIdx.x;
  int ebeg = blockIdx.x * EPB;
  int eend = min(E, ebeg + EPB);
  hist[tid] = 0;
  __syncthreads();
  int e0 = ebeg + tid * 16;
  int nE = eend - e0; if (nE < 0) nE = 0; if (nE > 16) nE = 16;
  int d[16], s[16], rk[16];
  if (nE == 16) {
#pragma unroll
    for (int q = 0; q < 4; ++q) {
      int4 dv = *(const int4*)(dst + e0 + q * 4);
      int4 sv = *(const int4*)(src + e0 + q * 4);
      d[q * 4 + 0] = dv.x; d[q * 4 + 1] = dv.y; d[q * 4 + 2] = dv.z; d[q * 4 + 3] = dv.w;
      s[q * 4 + 0] = sv.x; s[q * 4 + 1] = sv.y; s[q * 4 + 2] = sv.z; s[q * 4 + 3] = sv.w;
    }
  } else {
#pragma unroll
    for (int k = 0; k < 16; ++k) {
      if (k < nE) { d[k] = dst[e0 + k]; s[k] = src[e0 + k]; } else { d[k] = 0; s[k] = 0; }
    }
  }
#pragma unroll
  for (int k = 0; k < 16; ++k) rk[k] = (k < nE) ? atomicAdd(&hist[d[k] >> 8], 1) : 0;
  __syncthreads();
  int hc = hist[tid];
  sa[tid] = hc;
  base[tid] = (tid < NBKT && hc) ? atomicAdd(&gcur[tid], hc) : 0;
  __syncthreads();
  int* pin = sa; int* pout = sc;
  for (int st = 1; st < 512; st <<= 1) {
    pout[tid] = pin[tid] + ((tid >= st) ? pin[tid - st] : 0);
    __syncthreads();
    int* t = pin; pin = pout; pout = t;
  }
  loff[tid] = pin[tid] - hc;
  __syncthreads();
#pragma unroll
  for (int k = 0; k < 16; ++k) if (k < nE) {
    int bkt = d[k] >> 8;
    stage[loff[bkt] + rk[k]] = ((unsigned)s[k] << 8) | (unsigned)(d[k] & 255);
  }
  __syncthreads();
  int wv = tid >> 6, ln = tid & 63;
  for (int i = wv; i < NBKT; i += 8) {
    int c = hist[i], lo = loff[i], gb = base[i];
    for (int k = ln; k < c; k += 64) tmp[gb + k] = stage[lo + k];
  }
}

// ---------------- pass B: per-bucket build: rowptr, dinv, csr (rank-capture, no 2nd atomics) --

__global__ __launch_bounds__(512) void k_bucket_build(const unsigned* __restrict__ tmp, const int* __restrict__ bbase,
                                                      int* __restrict__ csr, int* __restrict__ rowptr,
                                                      float* __restrict__ dinv, int N) {
  int b = blockIdx.x;
  int tid = threadIdx.x;
  int node0 = b << 8;
  int nn = min(256, N - node0);
  int beg = bbase[b], end = bbase[b + 1], cnt = end - beg;
  __shared__ int h[256], off[256], cur[256];
  __shared__ unsigned short rk[MAXB];
  __shared__ int stage[MAXB];
  if (tid < 256) h[tid] = 0;
  __syncthreads();
  bool fast = (cnt <= MAXB);
  if (fast) {
    for (int e = beg + tid; e < end; e += 512) {
      unsigned p = tmp[e];
      rk[e - beg] = (unsigned short)atomicAdd(&h[p & 255], 1);
    }
  } else {
    for (int e = beg + tid; e < end; e += 512) atomicAdd(&h[tmp[e] & 255], 1);
  }
  __syncthreads();
  int deg = 0;
  if (tid < 256) { deg = h[tid]; off[tid] = deg; }
  __syncthreads();
  for (int st = 1; st < 256; st <<= 1) {
    int t = 0;
    if (tid < 256 && tid >= st) t = off[tid - st];
    __syncthreads();
    if (tid < 256) off[tid] += t;
    __syncthreads();
  }
  if (tid < 256) {
    int excl = off[tid] - deg;
    cur[tid] = excl;
    if (tid < nn) {
      rowptr[node0 + tid] = beg + excl;
      dinv[node0 + tid] = rsqrtf((float)(deg + 1));  // +1 = self loop
    }
  }
  __syncthreads();
  if (fast) {
    for (int e = beg + tid; e < end; e += 512) {
      unsigned p = tmp[e];
      stage[cur[p & 255] + (int)rk[e - beg]] = (int)(p >> 8);
    }
    __syncthreads();
    for (int k = tid; k < cnt; k += 512) csr[beg + k] = stage[k];
  } else {  // safety fallback (never taken for uniform-random dst)
    for (int e = beg + tid; e < end; e += 512) {
      unsigned p = tmp[e];
      int pos = atomicAdd(&cur[p & 255], 1);
      csr[beg + pos] = (int)(p >> 8);
    }
  }
}

// ---------------- MFMA GEMM + dinv prescale, bf16 sliced output ------------------------

template <int F_IN, int F_OUT>
__global__ __launch_bounds__(256) void k_gemm_mfma(const float* __restrict__ x, const float* __restrict__ W,
                                                   const float* __restrict__ dinv, unsigned short* __restrict__ g,
                                                   int N, int NT) {
  constexpr int NKS = F_IN / 32;   // K-steps of 32
  constexpr int NCT = F_OUT / 16;  // 16-col tiles (= output slices)
  int tid = threadIdx.x;
  int w = tid >> 6, lane = tid & 63;
  int lo = lane & 15, hi = lane >> 4;

  union U8 { bf16x8 v; unsigned u[4]; };
  U8 bf[NCT][NKS];
#pragma unroll
  for (int ct = 0; ct < NCT; ++ct)
#pragma unroll
    for (int ks = 0; ks < NKS; ++ks) {
      const float* wp = W + (size_t)(ks * 32 + hi * 8) * F_OUT + ct * 16 + lo;
      float f[8];
#pragma unroll
      for (int j = 0; j < 8; ++j) f[j] = wp[(size_t)j * F_OUT];
#pragma unroll
      for (int j = 0; j < 4; ++j)
        asm("v_cvt_pk_bf16_f32 %0, %1, %2" : "=v"(bf[ct][ks].u[j]) : "v"(f[2 * j]), "v"(f[2 * j + 1]));
    }

  for (int t = blockIdx.x * 4 + w; t < NT; t += gridDim.x * 4) {
    int row0 = t << 4;
    f32x4 acc[NCT];
#pragma unroll
    for (int ct = 0; ct < NCT; ++ct) acc[ct] = (f32x4){0.f, 0.f, 0.f, 0.f};
    int rl = row0 + lo; if (rl >= N) rl = N - 1;
    const float* xrow = x + (size_t)rl * F_IN;
#pragma unroll
    for (int ks = 0; ks < NKS; ++ks) {
      const float* xp = xrow + ks * 32 + hi * 8;
      float4 a0 = *(const float4*)xp;
      float4 a1 = *(const float4*)(xp + 4);
      U8 af;
      asm("v_cvt_pk_bf16_f32 %0, %1, %2" : "=v"(af.u[0]) : "v"(a0.x), "v"(a0.y));
      asm("v_cvt_pk_bf16_f32 %0, %1, %2" : "=v"(af.u[1]) : "v"(a0.z), "v"(a0.w));
      asm("v_cvt_pk_bf16_f32 %0, %1, %2" : "=v"(af.u[2]) : "v"(a1.x), "v"(a1.y));
      asm("v_cvt_pk_bf16_f32 %0, %1, %2" : "=v"(af.u[3]) : "v"(a1.z), "v"(a1.w));
#pragma unroll
      for (int ct = 0; ct < NCT; ++ct)
        acc[ct] = __builtin_amdgcn_mfma_f32_16x16x32_bf16(af.v, bf[ct][ks].v, acc[ct], 0, 0, 0);
    }
    float dvv[4];
    if (row0 + 16 <= N) {
      float4 d4 = *(const float4*)(dinv + row0 + (hi << 2));
      dvv[0] = d4.x; dvv[1] = d4.y; dvv[2] = d4.z; dvv[3] = d4.w;
    } else {
#pragma unroll
      for (int j = 0; j < 4; ++j) { int r = row0 + (hi << 2) + j; dvv[j] = dinv[r < N ? r : N - 1]; }
    }
#pragma unroll
    for (int ct = 0; ct < NCT; ++ct) {
      size_t sb = (size_t)ct * ((size_t)N * 16);
#pragma unroll
      for (int j = 0; j < 4; ++j) {
        int row = row0 + (hi << 2) + j;
        if (row < N) g[sb + (size_t)row * 16 + lo] = f2b(dvv[j] * acc[ct][j]);
      }
    }
  }
}

// ---------------- vector GEMM (layer 3 only: 32 -> 2) ----------------------------------

template <int F_IN, int F_OUT, int TPN, int ROWS>
__global__ __launch_bounds__(256) void k_gemm(const float* __restrict__ x, const float* __restrict__ W,
                                              const float* __restrict__ dinv, unsigned short* __restrict__ g, int N) {
  constexpr int VPT = F_OUT / TPN;
  constexpr int GROUPS = 256 / TPN;
  constexpr int NB = GROUPS * ROWS;
  __shared__ float ws[F_IN * F_OUT];
  __shared__ float xs[NB][F_IN];
  int tid = threadIdx.x;
  int base = blockIdx.x * NB;
  for (int i = tid; i < F_IN * F_OUT; i += 256) ws[i] = W[i];
  for (int i = tid; i < NB * F_IN; i += 256) {
    int r = i / F_IN, c = i - r * F_IN;
    int node = base + r;
    xs[r][c ^ (r & 31)] = (node < N) ? x[(size_t)node * F_IN + c] : 0.f;
  }
  __syncthreads();
  int fg = tid % TPN, f0 = fg * VPT;
  int ng = tid / TPN;
  int r0 = ng * ROWS;
  float acc[ROWS][VPT];
#pragma unroll
  for (int r = 0; r < ROWS; ++r)
#pragma unroll
    for (int j = 0; j < VPT; ++j) acc[r][j] = 0.f;
  for (int k = 0; k < F_IN; ++k) {
    float wv[VPT];
#pragma unroll
    for (int j = 0; j < VPT; ++j) wv[j] = ws[k * F_OUT + f0 + j];
#pragma unroll
    for (int r = 0; r < ROWS; ++r) {
      float xv = xs[r0 + r][k ^ ((r0 + r) & 31)];
#pragma unroll
      for (int j = 0; j < VPT; ++j) acc[r][j] += xv * wv[j];
    }
  }
#pragma unroll
  for (int r = 0; r < ROWS; ++r) {
    int node = base + r0 + r;
    if (node < N) {
      float dv = dinv[node];
#pragma unroll
      for (int j = 0; j < VPT; ++j) g[(size_t)node * F_OUT + f0 + j] = f2b(dv * acc[r][j]);
    }
  }
}

// ---------------- fused sliced CSR aggregation ------------------------------------------
// All slices in ONE launch; slice chosen by XCD (blockIdx % 8 round-robins XCDs on
// MI355X), so each XCD's L2 still sees exactly one 3.2MB slice working set.
// NSL=4: 2 XCDs per slice; NSL=2: 4 XCDs per slice. Perf heuristic only - correctness
// does not depend on the mapping.

template <int FOUT, int NSL, bool RELU>
__global__ __launch_bounds__(256) void k_aggf(const unsigned short* __restrict__ g,
                                              const int* __restrict__ rowptr, const int* __restrict__ csr,
                                              const float* __restrict__ dinv, const float* __restrict__ bias,
                                              float* __restrict__ out, int N) {
  int bx = blockIdx.x;
  int xcd = bx & 7;
  int slice, nb;
  if (NSL == 4) { slice = xcd >> 1; nb = (bx >> 3) * 2 + (xcd & 1); }
  else          { slice = xcd >> 2; nb = (bx >> 3) * 4 + (xcd & 3); }
  int t = nb * 256 + threadIdx.x;
  int grp = t >> 3;
  if (grp >= N) return;
  const unsigned short* gs = g + (size_t)slice * N * 16;
  int f0 = slice * 16;
  unsigned subB = ((unsigned)t & 7u) << 2;
  const char* gb = (const char*)gs;
  unsigned u = *(const unsigned*)(gb + ((((unsigned)grp) << 5) + subB));
  float acc0 = __uint_as_float(u << 16);
  float acc1 = __uint_as_float(u & 0xffff0000u);
  int beg = rowptr[grp], end = rowptr[grp + 1];
  int j = beg;
  for (; j < end && (j & 3); ++j) {
    unsigned v = *(const unsigned*)(gb + ((((unsigned)csr[j]) << 5) + subB));
    acc0 += __uint_as_float(v << 16);
    acc1 += __uint_as_float(v & 0xffff0000u);
  }
  for (; j + 4 <= end; j += 4) {
    int4 ss = *(const int4*)(csr + j);
    unsigned v0 = *(const unsigned*)(gb + ((((unsigned)ss.x) << 5) + subB));
    unsigned v1 = *(const unsigned*)(gb + ((((unsigned)ss.y) << 5) + subB));
    unsigned v2 = *(const unsigned*)(gb + ((((unsigned)ss.z) << 5) + subB));
    unsigned v3 = *(const unsigned*)(gb + ((((unsigned)ss.w) << 5) + subB));
    acc0 += __uint_as_float(v0 << 16); acc1 += __uint_as_float(v0 & 0xffff0000u);
    acc0 += __uint_as_float(v1 << 16); acc1 += __uint_as_float(v1 & 0xffff0000u);
    acc0 += __uint_as_float(v2 << 16); acc1 += __uint_as_float(v2 & 0xffff0000u);
    acc0 += __uint_as_float(v3 << 16); acc1 += __uint_as_float(v3 & 0xffff0000u);
  }
  for (; j < end; ++j) {
    unsigned v = *(const unsigned*)(gb + ((((unsigned)csr[j]) << 5) + subB));
    acc0 += __uint_as_float(v << 16);
    acc1 += __uint_as_float(v & 0xffff0000u);
  }
  float dv = dinv[grp];
  int fg = f0 + (int)(subB >> 1);
  float r0 = fmaf(dv, acc0, bias[fg]);
  float r1 = fmaf(dv, acc1, bias[fg + 1]);
  if (RELU) { r0 = fmaxf(r0, 0.f); r1 = fmaxf(r1, 0.f); }
  *(float2*)(out + (size_t)grp * FOUT + fg) = make_float2(r0, r1);
}

// ---------------- final layer aggregation (F=2, packed 4B rows) + log_softmax --------

__global__ __launch_bounds__(256) void k_final(const unsigned* __restrict__ g2, const int* __restrict__ rowptr,
                                               const int* __restrict__ csr, const float* __restrict__ dinv,
                                               const float* __restrict__ bias, float* __restrict__ out, int N) {
  int i = blockIdx.x * 256 + threadIdx.x;
  if (i >= N) return;
  const char* gb = (const char*)g2;
  unsigned s = *(const unsigned*)(gb + (((unsigned)i) << 2));
  float a0 = __uint_as_float(s << 16), a1 = __uint_as_float(s & 0xffff0000u);
  int beg = rowptr[i], end = rowptr[i + 1];
  for (int j = beg; j < end; ++j) {
    unsigned p = *(const unsigned*)(gb + (((unsigned)csr[j]) << 2));
    a0 += __uint_as_float(p << 16);
    a1 += __uint_as_float(p & 0xffff0000u);
  }
  float dv = dinv[i];
  float v0 = fmaf(dv, a0, bias[0]);
  float v1 = fmaf(dv, a1, bias[1]);
  float m = fmaxf(v0, v1);
  float lse = m + logf(expf(v0 - m) + expf(v1 - m));
  out[2 * (size_t)i] = v0 - lse;
  out[2 * (size_t)i + 1] = v1 - lse;
}

// ---------------- launch ----------------

extern "C" void kernel_launch(void* const* d_in, const int* in_sizes, int n_in,
                              void* d_out, int out_size, void* d_ws, size_t ws_size,
                              hipStream_t stream) {
  const float* x  = (const float*)d_in[0];
  const int*   ei = (const int*)d_in[1];
  const float* W1 = (const float*)d_in[2];
  const float* b1 = (const float*)d_in[3];
  const float* W2 = (const float*)d_in[4];
  const float* b2 = (const float*)d_in[5];
  const float* W3 = (const float*)d_in[6];
  const float* b3 = (const float*)d_in[7];
  float* out = (float*)d_out;

  int N = in_sizes[0] / 128;  // 100000
  int E = in_sizes[1] / 2;    // 3200000
  const int* src = ei;        // edge_index[0]
  const int* dst = ei + E;    // edge_index[1]
  int NBKT = (N + 255) >> 8;  // 391 coarse buckets of 256 nodes
  int NT = (N + 15) / 16;     // 6250 row-tiles

  char* w = (char*)d_ws;
  size_t off = 0;
  auto carve = [&](size_t bytes) -> char* {
    char* p = w + off;
    off = (off + bytes + 255) & ~(size_t)255;
    return p;
  };
  float* dinv   = (float*)carve((size_t)N * 4);
  int*   rowptr = (int*)carve((size_t)(N + 1) * 4);
  int*   bhist  = (int*)carve(2048);
  int*   bbase  = (int*)carve(2048 + 4);
  int*   gcur   = (int*)carve(2048);
  int*   csr    = (int*)carve((size_t)E * 4);
  size_t gsz = (size_t)N * 64 * 2;               // bf16 g buffer (sliced layout)
  if ((size_t)E * 4 > gsz) gsz = (size_t)E * 4;  // doubles as packed pair buffer
  unsigned short* gbuf = (unsigned short*)carve(gsz);
  float* hbuf   = (float*)carve((size_t)N * 64 * 4);
  unsigned* tmp = (unsigned*)gbuf;  // pair buffer dead once k_bucket_build finishes
  (void)ws_size; (void)n_in; (void)out_size;

  hipMemsetAsync(bhist, 0, (size_t)NBKT * 4, stream);
  k_bhist<<<782, 256, 0, stream>>>(dst, bhist, E, NBKT);
  k_bscan<<<1, 256, 0, stream>>>(bhist, bbase, gcur, rowptr, E, N, NBKT);
  k_bucket_scatter<<<(E + EPB - 1) / EPB, 512, 0, stream>>>(src, dst, gcur, tmp, E, NBKT);
  k_bucket_build<<<NBKT, 512, 0, stream>>>(tmp, bbase, csr, rowptr, dinv, N);

  // per-slice node-blocks: ceil(N*8/256) = 3125
  int nbs = (int)(((long long)N * 8 + 255) / 256);

  // layer 1: 128 -> 64 MFMA, relu; fused 4-slice agg (XCD-mapped slices)
  k_gemm_mfma<128, 64><<<782, 256, 0, stream>>>(x, W1, dinv, gbuf, N, NT);
  k_aggf<64, 4, true><<<8 * ((nbs + 1) / 2), 256, 0, stream>>>(gbuf, rowptr, csr, dinv, b1, hbuf, N);
  // layer 2: 64 -> 32 MFMA, relu; fused 2-slice agg
  k_gemm_mfma<64, 32><<<782, 256, 0, stream>>>(hbuf, W2, dinv, gbuf, N, NT);
  k_aggf<32, 2, true><<<8 * ((nbs + 3) / 4), 256, 0, stream>>>(gbuf, rowptr, csr, dinv, b2, hbuf, N);
  // layer 3: 32 -> 2 vector, log_softmax (g2 = 400KB, L2-resident as-is)
  k_gemm<32, 2, 1, 1><<<(N + 255) / 256, 256, 0, stream>>>(hbuf, W3, dinv, gbuf, N);
  k_final<<<(unsigned)((N + 255) / 256), 256, 0, stream>>>((const unsigned*)gbuf, rowptr, csr, dinv, b3, out, N);
}